// Round 16
// baseline (245.012 us; speedup 1.0000x reference)
//
#include <hip/hip_runtime.h>
#include <hip/hip_bf16.h>
#include <math.h>

#define N_USERS 50000
#define N_ITEMS 50000
#define NN      100000
#define HN      50000
#define E_PER_  400000
#define E_TOT   800000
#define FDIM    128
#define NH      4
#define HD      32
#define SCAN_CHUNK 1024
#define SCAN_NB    ((NN + SCAN_CHUNK - 1) / SCAN_CHUNK)   // 98
#define KQV_NB  ((N_USERS + 127) / 128)                   // 391 per side

typedef _Float16 h2 __attribute__((ext_vector_type(2)));
typedef _Float16 h8 __attribute__((ext_vector_type(8)));   // mfma f16 operand frag
typedef __attribute__((ext_vector_type(4))) float f32x4;

__device__ __forceinline__ float gelu_exact(float x) {
    return 0.5f * x * (1.0f + erff(x * 0.70710678118654752f));
}
__device__ __forceinline__ unsigned short f2h_bits(float f) {
    _Float16 h = (_Float16)f;
    union { _Float16 h; unsigned short u; } c; c.h = h; return c.u;
}
__device__ __forceinline__ h2 pkrtz(float a, float b) {
    return __builtin_bit_cast(h2, __builtin_amdgcn_cvt_pkrtz(a, b));
}
__device__ __forceinline__ unsigned h2_as_u(h2 x) {
    union { h2 h; unsigned u; } c; c.h = x; return c.u;
}
__device__ __forceinline__ h2 u_as_h2(unsigned x) {
    union { h2 h; unsigned u; } c; c.u = x; return c.h;
}
__device__ __forceinline__ h2 shfl_h2(h2 x, int m) {
    return u_as_h2((unsigned)__shfl_xor((int)h2_as_u(x), m));
}
// fragment slot index for A-operand W (16B per lane): n = matrix row, k = contraction
__device__ __forceinline__ size_t wfrag_idx(int n, int k) {
    int ch = n >> 7, nt = (n >> 4) & 7, lr = n & 15;
    int ks = k >> 5, lg = (k >> 3) & 3, e = k & 7;
    return ((size_t)(((ch * 8 + nt) * 4 + ks) * 64 + lg * 16 + lr)) * 8 + e;
}

// ---------------------------------------------------------------------------
// prep_all: [0,768) kqv-weight prep (rel-fused, frag layout);
//           [768,1024) W_out prep; [1024,...) zero cnt.  128 thr/block.
// ---------------------------------------------------------------------------
__global__ void prep_all(
    const float* __restrict__ W_u, const float* __restrict__ b_u,
    const float* __restrict__ W_i, const float* __restrict__ b_i,
    const float* __restrict__ Wk_rel, const float* __restrict__ Wv_rel,
    unsigned short* __restrict__ F_u, float* __restrict__ bias_u,
    unsigned short* __restrict__ F_i, float* __restrict__ bias_i,
    const float* __restrict__ Wo_u, unsigned short* __restrict__ Fo_u,
    const float* __restrict__ Wo_i, unsigned short* __restrict__ Fo_i,
    int* __restrict__ cnt)
{
    const int bid = blockIdx.x;
    if (bid < 768) {
        const int et = bid >= 384;
        const int n = bid - et * 384;   // 0..383
        const int k = threadIdx.x;      // 0..127
        const float* W = et ? W_i : W_u;
        const float* b = et ? b_i : b_u;
        unsigned short* F = et ? F_i : F_u;
        float* bias_f = et ? bias_i : bias_u;
        float s;
        if (n < 128) {
            int h = n >> 5, e = n & 31;
            const float* wr = Wk_rel + (size_t)(h * 2 + et) * 1024 + e;
            const float* wc = W + (size_t)k * 384 + h * 32;
            s = 0.f;
            for (int d = 0; d < 32; ++d) s = fmaf(wc[d], wr[d * 32], s);
            if (k == 0) {
                float bs = 0.f;
                for (int d = 0; d < 32; ++d) bs = fmaf(b[h * 32 + d], wr[d * 32], bs);
                bias_f[n] = bs;
            }
        } else if (n < 256) {
            s = W[(size_t)k * 384 + n];
            if (k == 0) bias_f[n] = b[n];
        } else {
            int h = (n - 256) >> 5, e = (n - 256) & 31;
            const float* wr = Wv_rel + (size_t)(h * 2 + et) * 1024 + e;
            const float* wc = W + (size_t)k * 384 + 256 + h * 32;
            s = 0.f;
            for (int d = 0; d < 32; ++d) s = fmaf(wc[d], wr[d * 32], s);
            if (k == 0) {
                float bs = 0.f;
                for (int d = 0; d < 32; ++d) bs = fmaf(b[256 + h * 32 + d], wr[d * 32], bs);
                bias_f[n] = bs;
            }
        }
        F[wfrag_idx(n, k)] = f2h_bits(s);
    } else if (bid < 1024) {
        int i = (bid - 768) * 128 + threadIdx.x;   // 0..32767
        int side = i >= 16384;
        int j = i - side * 16384;
        int n = j >> 7, k = j & 127;
        const float* W = side ? Wo_i : Wo_u;
        unsigned short* F = side ? Fo_i : Fo_u;
        F[wfrag_idx(n, k)] = f2h_bits(W[(size_t)k * 128 + n]);
    } else {
        int i = (bid - 1024) * 512 + threadIdx.x * 4;
        #pragma unroll
        for (int j = 0; j < 4; ++j)
            if (i + j < NN) cnt[i + j] = 0;
    }
}

// ---------------------------------------------------------------------------
// CSR helpers
// ---------------------------------------------------------------------------
__device__ __forceinline__ void edge_src_dst(
    int e, const int* __restrict__ edge_ui, const int* __restrict__ edge_iu,
    int& src, int& dst)
{
    if (e < E_PER_) {
        src = edge_ui[e];
        dst = edge_ui[E_PER_ + e] + N_USERS;
    } else {
        int e2 = e - E_PER_;
        src = N_USERS + edge_iu[e2];
        dst = edge_iu[E_PER_ + e2];
    }
}

__global__ __launch_bounds__(256) void hist_kernel(
    const int* __restrict__ edge_ui, const int* __restrict__ edge_iu,
    int* __restrict__ cnt)
{
    int e = blockIdx.x * blockDim.x + threadIdx.x;
    if (e >= E_TOT) return;
    int src, dst;
    edge_src_dst(e, edge_ui, edge_iu, src, dst);
    atomicAdd(cnt + dst, 1);
}

// ---------------------------------------------------------------------------
// KQV GEMM, LDS-free, f16 MFMA. BM=128, 3 chunks. (histogram un-fused: R15
// fusion pushed regs over the (256,3) cap -> spill -> 2x slower.)
// ---------------------------------------------------------------------------
__global__ __launch_bounds__(256, 3) void kqv_mfma(
    const float* __restrict__ X_u, const unsigned short* __restrict__ F_u,
    const float* __restrict__ bias_u,
    const float* __restrict__ X_i, const unsigned short* __restrict__ F_i,
    const float* __restrict__ bias_i,
    unsigned short* __restrict__ kk_b,
    unsigned short* __restrict__ q_b,
    unsigned short* __restrict__ vv_b)
{
    const int t = threadIdx.x;
    const int side = blockIdx.x >= KQV_NB;
    const int m0 = (blockIdx.x - side * KQV_NB) * 128;
    const float* X = side ? X_i : X_u;
    const unsigned short* F = side ? F_i : F_u;
    const float* bias = side ? bias_i : bias_u;
    const int side_off = side ? N_USERS : 0;
    const int M = N_USERS;

    const int wave = t >> 6, lane = t & 63;
    const int lr = lane & 15, lg = lane >> 4;
    const int rbase = m0 + wave * 32;

    h8 am[2][4];
    #pragma unroll
    for (int mt = 0; mt < 2; ++mt)
        #pragma unroll
        for (int ks = 0; ks < 4; ++ks) {
            int row = rbase + mt * 16 + lr;
            float4 a = make_float4(0.f, 0.f, 0.f, 0.f);
            float4 b4 = make_float4(0.f, 0.f, 0.f, 0.f);
            if (row < M) {
                const float* px = X + (size_t)row * 128 + ks * 32 + lg * 8;
                a  = *reinterpret_cast<const float4*>(px);
                b4 = *reinterpret_cast<const float4*>(px + 4);
            }
            union { h2 q[4]; h8 f; } u;
            u.q[0] = pkrtz(a.x, a.y);
            u.q[1] = pkrtz(a.z, a.w);
            u.q[2] = pkrtz(b4.x, b4.y);
            u.q[3] = pkrtz(b4.z, b4.w);
            am[mt][ks] = u.f;
        }

    #pragma unroll
    for (int ch = 0; ch < 3; ++ch) {
        f32x4 acc[2][8];
        const f32x4 zero = {0.f, 0.f, 0.f, 0.f};
        #pragma unroll
        for (int mt = 0; mt < 2; ++mt)
            #pragma unroll
            for (int nt = 0; nt < 8; ++nt) acc[mt][nt] = zero;

        h8 bc[4], bn[4];
        #pragma unroll
        for (int ks = 0; ks < 4; ++ks)
            bc[ks] = *reinterpret_cast<const h8*>(
                F + ((size_t)((ch * 8 + 0) * 4 + ks) * 64 + lane) * 8);

        #pragma unroll
        for (int nt = 0; nt < 8; ++nt) {
            if (nt < 7) {
                #pragma unroll
                for (int ks = 0; ks < 4; ++ks)
                    bn[ks] = *reinterpret_cast<const h8*>(
                        F + ((size_t)((ch * 8 + nt + 1) * 4 + ks) * 64 + lane) * 8);
            }
            #pragma unroll
            for (int mt = 0; mt < 2; ++mt)
                #pragma unroll
                for (int ks = 0; ks < 4; ++ks)
                    acc[mt][nt] = __builtin_amdgcn_mfma_f32_16x16x32_f16(
                        bc[ks], am[mt][ks], acc[mt][nt], 0, 0, 0);
            #pragma unroll
            for (int ks = 0; ks < 4; ++ks) bc[ks] = bn[ks];
        }

        unsigned short* arr = (ch == 0) ? kk_b : (ch == 1) ? q_b : vv_b;
        #pragma unroll
        for (int nt = 0; nt < 8; ++nt) {
            float4 bv = *reinterpret_cast<const float4*>(bias + ch * 128 + nt * 16 + lg * 4);
            #pragma unroll
            for (int mt = 0; mt < 2; ++mt) {
                int row = rbase + mt * 16 + lr;
                if (row < M) {
                    h2 lo = pkrtz(acc[mt][nt][0] + bv.x, acc[mt][nt][1] + bv.y);
                    h2 hi = pkrtz(acc[mt][nt][2] + bv.z, acc[mt][nt][3] + bv.w);
                    uint2 st = make_uint2(h2_as_u(lo), h2_as_u(hi));
                    *reinterpret_cast<uint2*>(
                        arr + (size_t)(side_off + row) * 128 + nt * 16 + lg * 4) = st;
                }
            }
        }
    }
}

// ---------------------------------------------------------------------------
// scan1: per-1024-chunk exclusive scan of cnt -> base, chunk totals -> bsum
// ---------------------------------------------------------------------------
__global__ __launch_bounds__(256) void scan1_kernel(
    const int* __restrict__ cnt, int* __restrict__ base, int* __restrict__ bsum)
{
    __shared__ int ssum[256];
    const int t = threadIdx.x;
    const int i0 = blockIdx.x * SCAN_CHUNK + t * 4;
    int v[4];
    #pragma unroll
    for (int j = 0; j < 4; ++j) v[j] = (i0 + j < NN) ? cnt[i0 + j] : 0;
    int tsum = v[0] + v[1] + v[2] + v[3];
    ssum[t] = tsum;
    __syncthreads();
    int run = tsum;
    for (int off = 1; off < 256; off <<= 1) {
        int o = (t >= off) ? ssum[t - off] : 0;
        __syncthreads();
        run += o;
        ssum[t] = run;
        __syncthreads();
    }
    int excl = run - tsum;
    int p = excl;
    #pragma unroll
    for (int j = 0; j < 4; ++j) {
        if (i0 + j < NN) base[i0 + j] = p;
        p += v[j];
    }
    if (t == 255) bsum[blockIdx.x] = run;
}

// scan3: adds chunk-prefix of bsum; writes cursor and packed (base,cnt) meta.
__global__ __launch_bounds__(256) void scan3_kernel(
    const int* __restrict__ base, const int* __restrict__ bsum,
    const int* __restrict__ cnt,
    int* __restrict__ cursor, int2* __restrict__ meta2)
{
    const int lane = threadIdx.x & 63;
    const int chunk = blockIdx.x >> 2;          // 256 threads, 1024-chunks
    int v0 = (lane < chunk) ? bsum[lane] : 0;
    int v1 = (64 + lane < chunk && 64 + lane < SCAN_NB) ? bsum[64 + lane] : 0;
    int s = v0 + v1;
    #pragma unroll
    for (int off = 1; off < 64; off <<= 1) s += __shfl_xor(s, off);
    int i = blockIdx.x * 256 + threadIdx.x;
    if (i < NN) {
        int b = base[i] + s;
        cursor[i] = b;
        meta2[i] = make_int2(b, cnt[i]);
    }
}

__global__ __launch_bounds__(256) void fill_kernel(
    const int* __restrict__ edge_ui, const int* __restrict__ edge_iu,
    int* __restrict__ cursor, int* __restrict__ esrc)
{
    int e = blockIdx.x * blockDim.x + threadIdx.x;
    if (e >= E_TOT) return;
    int src, dst;
    edge_src_dst(e, edge_ui, edge_iu, src, dst);
    int pos = atomicAdd(cursor + dst, 1);
    esrc[pos] = src;
}

// ---------------------------------------------------------------------------
// Fused attention v8 (f16, 2-node ILP): each wave processes nodes n (user)
// and n+HN (item) simultaneously with independent register state — doubles
// gathers in flight. 4 edges/iter each, intra-node prefetch, direct exp,
// fdot2 QK, half2 PV, reduce-scatter + all-lane gelu epilogue.
// ---------------------------------------------------------------------------
__global__ __launch_bounds__(256) void attn_fused(
    const unsigned short* __restrict__ q_b, const unsigned short* __restrict__ kk_b,
    const unsigned short* __restrict__ vv_b,
    const int2* __restrict__ meta2, const int* __restrict__ esrc,
    const float* __restrict__ p_ui, const float* __restrict__ p_iu,
    unsigned short* __restrict__ oa)
{
    const int wid  = (blockIdx.x * blockDim.x + threadIdx.x) >> 6;
    const int lane = threadIdx.x & 63;
    const int nw   = (gridDim.x * blockDim.x) >> 6;
    const int g    = lane >> 4;      // edge slot 0..3
    const int p    = lane & 15;      // dims 8p..8p+7
    const int h    = p >> 2;         // head
    const float rsd = 0.17677669529663687f;   // 1/sqrt(32)
    // node1 in [0,HN) is a user dst -> p_iu; node2 in [HN,NN) -> p_ui
    const float pr1 = p_iu[h] * rsd;
    const float pr2 = p_ui[h] * rsd;
    const int EC = E_TOT - 1;

    for (int n = wid; n < HN; n += nw) {
        const int n2 = n + HN;
        const int2 mt1 = meta2[n];
        const int2 mt2 = meta2[n2];
        union { uint4 u; h2 h[4]; } qu1, qu2;
        qu1.u = *reinterpret_cast<const uint4*>(q_b + (size_t)n  * 128 + p * 8);
        qu2.u = *reinterpret_cast<const uint4*>(q_b + (size_t)n2 * 128 + p * 8);
        float l1 = 0.f, l2 = 0.f;
        h2 a1[4], a2[4];
        #pragma unroll
        for (int i = 0; i < 4; ++i) { a1[i] = (h2)(_Float16)0; a2[i] = (h2)(_Float16)0; }
        const int s01 = mt1.x, c1 = mt1.y;
        const int s02 = mt2.x, c2 = mt2.y;

        bool val1 = g < c1, val2 = g < c2;
        int sr1 = esrc[min(s01 + (val1 ? g : 0), EC)];
        int sr2 = esrc[min(s02 + (val2 ? g : 0), EC)];
        uint4 k41 = *reinterpret_cast<const uint4*>(kk_b + (size_t)sr1 * 128 + p * 8);
        uint4 v41 = *reinterpret_cast<const uint4*>(vv_b + (size_t)sr1 * 128 + p * 8);
        uint4 k42 = *reinterpret_cast<const uint4*>(kk_b + (size_t)sr2 * 128 + p * 8);
        uint4 v42 = *reinterpret_cast<const uint4*>(vv_b + (size_t)sr2 * 128 + p * 8);

        for (int j = 0; j < c1 || j < c2; j += 4) {
            uint4 k41n, v41n, k42n, v42n;
            bool v1n = false, v2n = false;
            if (j + 4 < c1) {
                int jn = j + 4 + g;
                v1n = jn < c1;
                int srn = esrc[s01 + (v1n ? jn : 0)];
                k41n = *reinterpret_cast<const uint4*>(kk_b + (size_t)srn * 128 + p * 8);
                v41n = *reinterpret_cast<const uint4*>(vv_b + (size_t)srn * 128 + p * 8);
            }
            if (j + 4 < c2) {
                int jn = j + 4 + g;
                v2n = jn < c2;
                int srn = esrc[s02 + (v2n ? jn : 0)];
                k42n = *reinterpret_cast<const uint4*>(kk_b + (size_t)srn * 128 + p * 8);
                v42n = *reinterpret_cast<const uint4*>(vv_b + (size_t)srn * 128 + p * 8);
            }

            if (j < c1) {
                union { uint4 u; h2 h[4]; } ku, vu;
                ku.u = k41; vu.u = v41;
                float s = 0.f;
                s = __builtin_amdgcn_fdot2(qu1.h[0], ku.h[0], s, false);
                s = __builtin_amdgcn_fdot2(qu1.h[1], ku.h[1], s, false);
                s = __builtin_amdgcn_fdot2(qu1.h[2], ku.h[2], s, false);
                s = __builtin_amdgcn_fdot2(qu1.h[3], ku.h[3], s, false);
                s += __shfl_xor(s, 1);
                s += __shfl_xor(s, 2);
                float w = val1 ? __expf(s * pr1) : 0.f;
                l1 += w;
                h2 wpk = pkrtz(w, w);
                #pragma unroll
                for (int i = 0; i < 4; ++i) a1[i] += vu.h[i] * wpk;
            }
            if (j < c2) {
                union { uint4 u; h2 h[4]; } ku, vu;
                ku.u = k42; vu.u = v42;
                float s = 0.f;
                s = __builtin_amdgcn_fdot2(qu2.h[0], ku.h[0], s, false);
                s = __builtin_amdgcn_fdot2(qu2.h[1], ku.h[1], s, false);
                s = __builtin_amdgcn_fdot2(qu2.h[2], ku.h[2], s, false);
                s = __builtin_amdgcn_fdot2(qu2.h[3], ku.h[3], s, false);
                s += __shfl_xor(s, 1);
                s += __shfl_xor(s, 2);
                float w = val2 ? __expf(s * pr2) : 0.f;
                l2 += w;
                h2 wpk = pkrtz(w, w);
                #pragma unroll
                for (int i = 0; i < 4; ++i) a2[i] += vu.h[i] * wpk;
            }

            k41 = k41n; v41 = v41n; val1 = v1n;
            k42 = k42n; v42 = v42n; val2 = v2n;
        }

        // denominators over the 4 edge groups
        l1 += __shfl_xor(l1, 16); l1 += __shfl_xor(l1, 32);
        l2 += __shfl_xor(l2, 16); l2 += __shfl_xor(l2, 32);

        // reduce-scatter both acc sets across groups (half2)
        const bool b1 = (g & 2) != 0;
        h2 r41[2], r42[2];
        #pragma unroll
        for (int i = 0; i < 2; ++i) {
            h2 m1 = b1 ? a1[2 + i] : a1[i];
            h2 s1 = b1 ? a1[i] : a1[2 + i];
            r41[i] = m1 + shfl_h2(s1, 32);
            h2 m2 = b1 ? a2[2 + i] : a2[i];
            h2 s2 = b1 ? a2[i] : a2[2 + i];
            r42[i] = m2 + shfl_h2(s2, 32);
        }
        const bool b0 = (g & 1) != 0;
        h2 m1 = b0 ? r41[1] : r41[0];
        h2 s1 = b0 ? r41[0] : r41[1];
        h2 r21 = m1 + shfl_h2(s1, 16);
        h2 m2 = b0 ? r42[1] : r42[0];
        h2 s2 = b0 ? r42[0] : r42[1];
        h2 r22 = m2 + shfl_h2(s2, 16);

        float inv1 = 1.0f / (l1 + 1e-16f);
        float inv2 = 1.0f / (l2 + 1e-16f);
        unsigned pk1 = h2_as_u(pkrtz(gelu_exact((float)r21[0] * inv1),
                                     gelu_exact((float)r21[1] * inv1)));
        unsigned pk2 = h2_as_u(pkrtz(gelu_exact((float)r22[0] * inv2),
                                     gelu_exact((float)r22[1] * inv2)));
        *reinterpret_cast<unsigned*>(oa + (size_t)n  * 128 + p * 8 + 2 * g) = pk1;
        *reinterpret_cast<unsigned*>(oa + (size_t)n2 * 128 + p * 8 + 2 * g) = pk2;
    }
}

// ---------------------------------------------------------------------------
// Final GEMM, LDS-free (both sides), f16 MFMA:
// out = sg*(oa_gelu @ Wo + bo) + (1-sg)*x.  dbuf weight frags, (256,3).
// ---------------------------------------------------------------------------
__global__ __launch_bounds__(256, 3) void final_mfma(
    const unsigned short* __restrict__ oa,   // [NN][128] f16, gelu'd
    const float* __restrict__ x_u, const unsigned short* __restrict__ F_u,
    const float* __restrict__ bo_u, const float* __restrict__ skip_u,
    const float* __restrict__ x_i, const unsigned short* __restrict__ F_i,
    const float* __restrict__ bo_i, const float* __restrict__ skip_i,
    float* __restrict__ out)
{
    const int t = threadIdx.x;
    const int side = blockIdx.x >= KQV_NB;
    const int m0 = (blockIdx.x - side * KQV_NB) * 128;
    const float* x = side ? x_i : x_u;
    const unsigned short* F = side ? F_i : F_u;
    const float* bo = side ? bo_i : bo_u;
    const float* skip = side ? skip_i : skip_u;
    const int row_off = side ? N_USERS : 0;
    const int M = N_USERS;

    const int wave = t >> 6, lane = t & 63;
    const int lr = lane & 15, lg = lane >> 4;
    const int rbase = m0 + wave * 32;

    h8 am[2][4];
    const h8 bz = {0, 0, 0, 0, 0, 0, 0, 0};
    #pragma unroll
    for (int mt = 0; mt < 2; ++mt)
        #pragma unroll
        for (int ks = 0; ks < 4; ++ks) {
            int row = rbase + mt * 16 + lr;
            am[mt][ks] = (row < M)
                ? *reinterpret_cast<const h8*>(
                      oa + (size_t)(row_off + row) * 128 + ks * 32 + lg * 8)
                : bz;
        }

    f32x4 acc[2][8];
    const f32x4 zero = {0.f, 0.f, 0.f, 0.f};
    #pragma unroll
    for (int mt = 0; mt < 2; ++mt)
        #pragma unroll
        for (int nt = 0; nt < 8; ++nt) acc[mt][nt] = zero;

    h8 bc[4], bn[4];
    #pragma unroll
    for (int ks = 0; ks < 4; ++ks)
        bc[ks] = *reinterpret_cast<const h8*>(
            F + ((size_t)(0 * 4 + ks) * 64 + lane) * 8);

    #pragma unroll
    for (int nt = 0; nt < 8; ++nt) {
        if (nt < 7) {
            #pragma unroll
            for (int ks = 0; ks < 4; ++ks)
                bn[ks] = *reinterpret_cast<const h8*>(
                    F + ((size_t)((nt + 1) * 4 + ks) * 64 + lane) * 8);
        }
        #pragma unroll
        for (int mt = 0; mt < 2; ++mt)
            #pragma unroll
            for (int ks = 0; ks < 4; ++ks)
                acc[mt][nt] = __builtin_amdgcn_mfma_f32_16x16x32_f16(
                    bc[ks], am[mt][ks], acc[mt][nt], 0, 0, 0);
        #pragma unroll
        for (int ks = 0; ks < 4; ++ks) bc[ks] = bn[ks];
    }

    const float sg = 1.0f / (1.0f + expf(-skip[0]));
    #pragma unroll
    for (int nt = 0; nt < 8; ++nt) {
        float4 bv = *reinterpret_cast<const float4*>(bo + nt * 16 + lg * 4);
        #pragma unroll
        for (int mt = 0; mt < 2; ++mt) {
            int row = rbase + mt * 16 + lr;
            if (row < M) {
                float4 xv = *reinterpret_cast<const float4*>(
                    x + (size_t)row * 128 + nt * 16 + lg * 4);
                float4 res;
                res.x = sg * (acc[mt][nt][0] + bv.x) + (1.f - sg) * xv.x;
                res.y = sg * (acc[mt][nt][1] + bv.y) + (1.f - sg) * xv.y;
                res.z = sg * (acc[mt][nt][2] + bv.z) + (1.f - sg) * xv.z;
                res.w = sg * (acc[mt][nt][3] + bv.w) + (1.f - sg) * xv.w;
                *reinterpret_cast<float4*>(
                    out + (size_t)(row_off + row) * 128 + nt * 16 + lg * 4) = res;
            }
        }
    }
}

// ---------------------------------------------------------------------------
extern "C" void kernel_launch(void* const* d_in, const int* in_sizes, int n_in,
                              void* d_out, int out_size, void* d_ws, size_t ws_size,
                              hipStream_t stream)
{
    const float* x_user     = (const float*)d_in[0];
    const float* x_item     = (const float*)d_in[1];
    const float* W_kqv_user = (const float*)d_in[2];
    const float* b_kqv_user = (const float*)d_in[3];
    const float* W_kqv_item = (const float*)d_in[4];
    const float* b_kqv_item = (const float*)d_in[5];
    const float* Wk_rel     = (const float*)d_in[6];
    const float* Wv_rel     = (const float*)d_in[7];
    const float* W_out_user = (const float*)d_in[8];
    const float* b_out_user = (const float*)d_in[9];
    const float* W_out_item = (const float*)d_in[10];
    const float* b_out_item = (const float*)d_in[11];
    const float* skip_user  = (const float*)d_in[12];
    const float* skip_item  = (const float*)d_in[13];
    const float* p_ui       = (const float*)d_in[14];
    const float* p_iu       = (const float*)d_in[15];
    const int*   edge_ui    = (const int*)d_in[16];
    const int*   edge_iu    = (const int*)d_in[17];

    const size_t NODE_F = (size_t)NN * FDIM;     // 12.8M elems
    char* w = (char*)d_ws;
    size_t off = 0;
    auto alloc = [&](size_t bytes) {
        char* p = w + off;
        off += (bytes + 255) & ~(size_t)255;
        return p;
    };
    unsigned short* q_b   = (unsigned short*)alloc(NODE_F * 2);
    unsigned short* kk_b  = (unsigned short*)alloc(NODE_F * 2);
    unsigned short* vv_b  = (unsigned short*)alloc(NODE_F * 2);
    unsigned short* oa_b  = (unsigned short*)alloc(NODE_F * 2);
    int* esrc   = (int*)alloc((size_t)E_TOT * 4);
    int* cnt    = (int*)alloc((size_t)NN * 4);
    int* base   = (int*)alloc((size_t)NN * 4);
    int* cursor = (int*)alloc((size_t)NN * 4);
    int* bsum   = (int*)alloc((size_t)SCAN_NB * 4);
    int2* meta2 = (int2*)alloc((size_t)NN * 8);
    unsigned short* F_u    = (unsigned short*)alloc(384 * 128 * 2);
    unsigned short* F_i    = (unsigned short*)alloc(384 * 128 * 2);
    float*          bias_u = (float*)alloc(384 * 4);
    float*          bias_i = (float*)alloc(384 * 4);
    unsigned short* Fo_u   = (unsigned short*)alloc(128 * 128 * 2);
    unsigned short* Fo_i   = (unsigned short*)alloc(128 * 128 * 2);

    // prep: kqv weights + wo weights + cnt zeroing (one launch)
    const int ZB = (NN + 511) / 512;   // 196
    prep_all<<<1024 + ZB, 128, 0, stream>>>(
        W_kqv_user, b_kqv_user, W_kqv_item, b_kqv_item, Wk_rel, Wv_rel,
        F_u, bias_u, F_i, bias_i,
        W_out_user, Fo_u, W_out_item, Fo_i, cnt);

    // edge histogram (separate: fusing into kqv spilled regs, R15 lesson)
    hist_kernel<<<(E_TOT + 255) / 256, 256, 0, stream>>>(edge_ui, edge_iu, cnt);

    // fused KQV(+rel) GEMM, both sides
    kqv_mfma<<<2 * KQV_NB, 256, 0, stream>>>(x_user, F_u, bias_u,
                                             x_item, F_i, bias_i,
                                             kk_b, q_b, vv_b);

    // CSR: scan + fill
    scan1_kernel<<<SCAN_NB, 256, 0, stream>>>(cnt, base, bsum);
    scan3_kernel<<<(NN + 255) / 256, 256, 0, stream>>>(base, bsum, cnt, cursor, meta2);
    fill_kernel<<<(E_TOT + 255) / 256, 256, 0, stream>>>(edge_ui, edge_iu, cursor, esrc);

    attn_fused<<<2048, 256, 0, stream>>>(q_b, kk_b, vv_b, meta2, esrc,
                                         p_ui, p_iu, oa_b);

    // final GEMM, both sides (gelu already applied in attn)
    final_mfma<<<2 * KQV_NB, 256, 0, stream>>>(
        oa_b, x_user, Fo_u, b_out_user, skip_user,
        x_item, Fo_i, b_out_item, skip_item, (float*)d_out);
}

// Round 17
// 236.844 us; speedup vs baseline: 1.0345x; 1.0345x over previous
//
#include <hip/hip_runtime.h>
#include <hip/hip_bf16.h>
#include <math.h>

#define N_USERS 50000
#define N_ITEMS 50000
#define NN      100000
#define HN      50000
#define E_PER_  400000
#define E_TOT   800000
#define FDIM    128
#define NH      4
#define HD      32
#define SCAN_CHUNK 1024
#define SCAN_NB    ((NN + SCAN_CHUNK - 1) / SCAN_CHUNK)   // 98
#define KQV_NB  ((N_USERS + 127) / 128)                   // 391 per side

typedef _Float16 h2 __attribute__((ext_vector_type(2)));
typedef _Float16 h8 __attribute__((ext_vector_type(8)));   // mfma f16 operand frag
typedef __attribute__((ext_vector_type(4))) float f32x4;

__device__ __forceinline__ float gelu_exact(float x) {
    return 0.5f * x * (1.0f + erff(x * 0.70710678118654752f));
}
__device__ __forceinline__ unsigned short f2h_bits(float f) {
    _Float16 h = (_Float16)f;
    union { _Float16 h; unsigned short u; } c; c.h = h; return c.u;
}
__device__ __forceinline__ h2 pkrtz(float a, float b) {
    return __builtin_bit_cast(h2, __builtin_amdgcn_cvt_pkrtz(a, b));
}
__device__ __forceinline__ unsigned h2_as_u(h2 x) {
    union { h2 h; unsigned u; } c; c.h = x; return c.u;
}
__device__ __forceinline__ h2 u_as_h2(unsigned x) {
    union { h2 h; unsigned u; } c; c.u = x; return c.h;
}
__device__ __forceinline__ h2 shfl_h2(h2 x, int m) {
    return u_as_h2((unsigned)__shfl_xor((int)h2_as_u(x), m));
}
// fragment slot index for A-operand W (16B per lane): n = matrix row, k = contraction
__device__ __forceinline__ size_t wfrag_idx(int n, int k) {
    int ch = n >> 7, nt = (n >> 4) & 7, lr = n & 15;
    int ks = k >> 5, lg = (k >> 3) & 3, e = k & 7;
    return ((size_t)(((ch * 8 + nt) * 4 + ks) * 64 + lg * 16 + lr)) * 8 + e;
}

// ---------------------------------------------------------------------------
// prep_all: [0,768) kqv-weight prep (rel-fused, frag layout);
//           [768,1024) W_out prep; [1024,...) zero cnt.  128 thr/block.
// ---------------------------------------------------------------------------
__global__ void prep_all(
    const float* __restrict__ W_u, const float* __restrict__ b_u,
    const float* __restrict__ W_i, const float* __restrict__ b_i,
    const float* __restrict__ Wk_rel, const float* __restrict__ Wv_rel,
    unsigned short* __restrict__ F_u, float* __restrict__ bias_u,
    unsigned short* __restrict__ F_i, float* __restrict__ bias_i,
    const float* __restrict__ Wo_u, unsigned short* __restrict__ Fo_u,
    const float* __restrict__ Wo_i, unsigned short* __restrict__ Fo_i,
    int* __restrict__ cnt)
{
    const int bid = blockIdx.x;
    if (bid < 768) {
        const int et = bid >= 384;
        const int n = bid - et * 384;   // 0..383
        const int k = threadIdx.x;      // 0..127
        const float* W = et ? W_i : W_u;
        const float* b = et ? b_i : b_u;
        unsigned short* F = et ? F_i : F_u;
        float* bias_f = et ? bias_i : bias_u;
        float s;
        if (n < 128) {
            int h = n >> 5, e = n & 31;
            const float* wr = Wk_rel + (size_t)(h * 2 + et) * 1024 + e;
            const float* wc = W + (size_t)k * 384 + h * 32;
            s = 0.f;
            for (int d = 0; d < 32; ++d) s = fmaf(wc[d], wr[d * 32], s);
            if (k == 0) {
                float bs = 0.f;
                for (int d = 0; d < 32; ++d) bs = fmaf(b[h * 32 + d], wr[d * 32], bs);
                bias_f[n] = bs;
            }
        } else if (n < 256) {
            s = W[(size_t)k * 384 + n];
            if (k == 0) bias_f[n] = b[n];
        } else {
            int h = (n - 256) >> 5, e = (n - 256) & 31;
            const float* wr = Wv_rel + (size_t)(h * 2 + et) * 1024 + e;
            const float* wc = W + (size_t)k * 384 + 256 + h * 32;
            s = 0.f;
            for (int d = 0; d < 32; ++d) s = fmaf(wc[d], wr[d * 32], s);
            if (k == 0) {
                float bs = 0.f;
                for (int d = 0; d < 32; ++d) bs = fmaf(b[256 + h * 32 + d], wr[d * 32], bs);
                bias_f[n] = bs;
            }
        }
        F[wfrag_idx(n, k)] = f2h_bits(s);
    } else if (bid < 1024) {
        int i = (bid - 768) * 128 + threadIdx.x;   // 0..32767
        int side = i >= 16384;
        int j = i - side * 16384;
        int n = j >> 7, k = j & 127;
        const float* W = side ? Wo_i : Wo_u;
        unsigned short* F = side ? Fo_i : Fo_u;
        F[wfrag_idx(n, k)] = f2h_bits(W[(size_t)k * 128 + n]);
    } else {
        int i = (bid - 1024) * 512 + threadIdx.x * 4;
        #pragma unroll
        for (int j = 0; j < 4; ++j)
            if (i + j < NN) cnt[i + j] = 0;
    }
}

// ---------------------------------------------------------------------------
// CSR helpers
// ---------------------------------------------------------------------------
__device__ __forceinline__ void edge_src_dst(
    int e, const int* __restrict__ edge_ui, const int* __restrict__ edge_iu,
    int& src, int& dst)
{
    if (e < E_PER_) {
        src = edge_ui[e];
        dst = edge_ui[E_PER_ + e] + N_USERS;
    } else {
        int e2 = e - E_PER_;
        src = N_USERS + edge_iu[e2];
        dst = edge_iu[E_PER_ + e2];
    }
}

__global__ __launch_bounds__(256) void hist_kernel(
    const int* __restrict__ edge_ui, const int* __restrict__ edge_iu,
    int* __restrict__ cnt)
{
    int e = blockIdx.x * blockDim.x + threadIdx.x;
    if (e >= E_TOT) return;
    int src, dst;
    edge_src_dst(e, edge_ui, edge_iu, src, dst);
    atomicAdd(cnt + dst, 1);
}

// ---------------------------------------------------------------------------
// KQV GEMM, LDS-free, f16 MFMA. BM=128, 3 chunks.
// ---------------------------------------------------------------------------
__global__ __launch_bounds__(256, 3) void kqv_mfma(
    const float* __restrict__ X_u, const unsigned short* __restrict__ F_u,
    const float* __restrict__ bias_u,
    const float* __restrict__ X_i, const unsigned short* __restrict__ F_i,
    const float* __restrict__ bias_i,
    unsigned short* __restrict__ kk_b,
    unsigned short* __restrict__ q_b,
    unsigned short* __restrict__ vv_b)
{
    const int t = threadIdx.x;
    const int side = blockIdx.x >= KQV_NB;
    const int m0 = (blockIdx.x - side * KQV_NB) * 128;
    const float* X = side ? X_i : X_u;
    const unsigned short* F = side ? F_i : F_u;
    const float* bias = side ? bias_i : bias_u;
    const int side_off = side ? N_USERS : 0;
    const int M = N_USERS;

    const int wave = t >> 6, lane = t & 63;
    const int lr = lane & 15, lg = lane >> 4;
    const int rbase = m0 + wave * 32;

    h8 am[2][4];
    #pragma unroll
    for (int mt = 0; mt < 2; ++mt)
        #pragma unroll
        for (int ks = 0; ks < 4; ++ks) {
            int row = rbase + mt * 16 + lr;
            float4 a = make_float4(0.f, 0.f, 0.f, 0.f);
            float4 b4 = make_float4(0.f, 0.f, 0.f, 0.f);
            if (row < M) {
                const float* px = X + (size_t)row * 128 + ks * 32 + lg * 8;
                a  = *reinterpret_cast<const float4*>(px);
                b4 = *reinterpret_cast<const float4*>(px + 4);
            }
            union { h2 q[4]; h8 f; } u;
            u.q[0] = pkrtz(a.x, a.y);
            u.q[1] = pkrtz(a.z, a.w);
            u.q[2] = pkrtz(b4.x, b4.y);
            u.q[3] = pkrtz(b4.z, b4.w);
            am[mt][ks] = u.f;
        }

    #pragma unroll
    for (int ch = 0; ch < 3; ++ch) {
        f32x4 acc[2][8];
        const f32x4 zero = {0.f, 0.f, 0.f, 0.f};
        #pragma unroll
        for (int mt = 0; mt < 2; ++mt)
            #pragma unroll
            for (int nt = 0; nt < 8; ++nt) acc[mt][nt] = zero;

        h8 bc[4], bn[4];
        #pragma unroll
        for (int ks = 0; ks < 4; ++ks)
            bc[ks] = *reinterpret_cast<const h8*>(
                F + ((size_t)((ch * 8 + 0) * 4 + ks) * 64 + lane) * 8);

        #pragma unroll
        for (int nt = 0; nt < 8; ++nt) {
            if (nt < 7) {
                #pragma unroll
                for (int ks = 0; ks < 4; ++ks)
                    bn[ks] = *reinterpret_cast<const h8*>(
                        F + ((size_t)((ch * 8 + nt + 1) * 4 + ks) * 64 + lane) * 8);
            }
            #pragma unroll
            for (int mt = 0; mt < 2; ++mt)
                #pragma unroll
                for (int ks = 0; ks < 4; ++ks)
                    acc[mt][nt] = __builtin_amdgcn_mfma_f32_16x16x32_f16(
                        bc[ks], am[mt][ks], acc[mt][nt], 0, 0, 0);
            #pragma unroll
            for (int ks = 0; ks < 4; ++ks) bc[ks] = bn[ks];
        }

        unsigned short* arr = (ch == 0) ? kk_b : (ch == 1) ? q_b : vv_b;
        #pragma unroll
        for (int nt = 0; nt < 8; ++nt) {
            float4 bv = *reinterpret_cast<const float4*>(bias + ch * 128 + nt * 16 + lg * 4);
            #pragma unroll
            for (int mt = 0; mt < 2; ++mt) {
                int row = rbase + mt * 16 + lr;
                if (row < M) {
                    h2 lo = pkrtz(acc[mt][nt][0] + bv.x, acc[mt][nt][1] + bv.y);
                    h2 hi = pkrtz(acc[mt][nt][2] + bv.z, acc[mt][nt][3] + bv.w);
                    uint2 st = make_uint2(h2_as_u(lo), h2_as_u(hi));
                    *reinterpret_cast<uint2*>(
                        arr + (size_t)(side_off + row) * 128 + nt * 16 + lg * 4) = st;
                }
            }
        }
    }
}

// ---------------------------------------------------------------------------
// scan1: per-1024-chunk exclusive scan of cnt -> base, chunk totals -> bsum
// ---------------------------------------------------------------------------
__global__ __launch_bounds__(256) void scan1_kernel(
    const int* __restrict__ cnt, int* __restrict__ base, int* __restrict__ bsum)
{
    __shared__ int ssum[256];
    const int t = threadIdx.x;
    const int i0 = blockIdx.x * SCAN_CHUNK + t * 4;
    int v[4];
    #pragma unroll
    for (int j = 0; j < 4; ++j) v[j] = (i0 + j < NN) ? cnt[i0 + j] : 0;
    int tsum = v[0] + v[1] + v[2] + v[3];
    ssum[t] = tsum;
    __syncthreads();
    int run = tsum;
    for (int off = 1; off < 256; off <<= 1) {
        int o = (t >= off) ? ssum[t - off] : 0;
        __syncthreads();
        run += o;
        ssum[t] = run;
        __syncthreads();
    }
    int excl = run - tsum;
    int p = excl;
    #pragma unroll
    for (int j = 0; j < 4; ++j) {
        if (i0 + j < NN) base[i0 + j] = p;
        p += v[j];
    }
    if (t == 255) bsum[blockIdx.x] = run;
}

// scan3: adds chunk-prefix of bsum; writes cursor and packed (base,cnt) meta.
__global__ __launch_bounds__(256) void scan3_kernel(
    const int* __restrict__ base, const int* __restrict__ bsum,
    const int* __restrict__ cnt,
    int* __restrict__ cursor, int2* __restrict__ meta2)
{
    const int lane = threadIdx.x & 63;
    const int chunk = blockIdx.x >> 2;          // 256 threads, 1024-chunks
    int v0 = (lane < chunk) ? bsum[lane] : 0;
    int v1 = (64 + lane < chunk && 64 + lane < SCAN_NB) ? bsum[64 + lane] : 0;
    int s = v0 + v1;
    #pragma unroll
    for (int off = 1; off < 64; off <<= 1) s += __shfl_xor(s, off);
    int i = blockIdx.x * 256 + threadIdx.x;
    if (i < NN) {
        int b = base[i] + s;
        cursor[i] = b;
        meta2[i] = make_int2(b, cnt[i]);
    }
}

__global__ __launch_bounds__(256) void fill_kernel(
    const int* __restrict__ edge_ui, const int* __restrict__ edge_iu,
    int* __restrict__ cursor, int* __restrict__ esrc)
{
    int e = blockIdx.x * blockDim.x + threadIdx.x;
    if (e >= E_TOT) return;
    int src, dst;
    edge_src_dst(e, edge_ui, edge_iu, src, dst);
    int pos = atomicAdd(cursor + dst, 1);
    esrc[pos] = src;
}

// ---------------------------------------------------------------------------
// Fused attention v7 (f16, 1-node/wave — R14 local optimum): FOUR edges/iter
// (g=lane>>4, p=lane&15 -> dims 8p..8p+7, head h=p>>2), intra-node prefetch,
// direct exp, fdot2 QK, half2 PV, reduce-scatter + all-lane gelu epilogue.
// (2-node ILP (R16) and node-rotation (R11) both lost to occupancy.)
// ---------------------------------------------------------------------------
__global__ __launch_bounds__(256) void attn_fused(
    const unsigned short* __restrict__ q_b, const unsigned short* __restrict__ kk_b,
    const unsigned short* __restrict__ vv_b,
    const int2* __restrict__ meta2, const int* __restrict__ esrc,
    const float* __restrict__ p_ui, const float* __restrict__ p_iu,
    unsigned short* __restrict__ oa)
{
    const int wid  = (blockIdx.x * blockDim.x + threadIdx.x) >> 6;
    const int lane = threadIdx.x & 63;
    const int nw   = (gridDim.x * blockDim.x) >> 6;
    const int g    = lane >> 4;      // edge slot 0..3
    const int p    = lane & 15;      // dims 8p..8p+7
    const int h    = p >> 2;         // head
    const float rsd = 0.17677669529663687f;   // 1/sqrt(32)
    const float pu = p_ui[h], pi = p_iu[h];

    for (int n = wid; n < NN; n += nw) {
        const float pr = (n >= N_USERS) ? pu : pi;
        union { uint4 u; h2 h[4]; } qu;
        qu.u = *reinterpret_cast<const uint4*>(q_b + (size_t)n * 128 + p * 8);
        float l = 0.f;
        h2 acc2[4];
        #pragma unroll
        for (int i = 0; i < 4; ++i) acc2[i] = (h2)(_Float16)0;
        const int2 mt = meta2[n];
        const int s0 = mt.x, c = mt.y;

        if (c > 0) {
            bool valid = g < c;
            int src = esrc[s0 + (valid ? g : 0)];
            uint4 k4 = *reinterpret_cast<const uint4*>(kk_b + (size_t)src * 128 + p * 8);
            uint4 v4 = *reinterpret_cast<const uint4*>(vv_b + (size_t)src * 128 + p * 8);

            for (int j = 0; j < c; j += 4) {
                uint4 k4n, v4n;
                bool validn = false;
                if (j + 4 < c) {
                    int jn = j + 4 + g;
                    validn = jn < c;
                    int srcn = esrc[s0 + (validn ? jn : 0)];
                    k4n = *reinterpret_cast<const uint4*>(kk_b + (size_t)srcn * 128 + p * 8);
                    v4n = *reinterpret_cast<const uint4*>(vv_b + (size_t)srcn * 128 + p * 8);
                }

                union { uint4 u; h2 h[4]; } ku, vu;
                ku.u = k4; vu.u = v4;
                float s = 0.f;
                s = __builtin_amdgcn_fdot2(qu.h[0], ku.h[0], s, false);
                s = __builtin_amdgcn_fdot2(qu.h[1], ku.h[1], s, false);
                s = __builtin_amdgcn_fdot2(qu.h[2], ku.h[2], s, false);
                s = __builtin_amdgcn_fdot2(qu.h[3], ku.h[3], s, false);
                s += __shfl_xor(s, 1);
                s += __shfl_xor(s, 2);       // head = 4 lanes x 8 dims
                float w = valid ? __expf(s * pr * rsd) : 0.f;
                l += w;
                h2 wpk = pkrtz(w, w);
                #pragma unroll
                for (int i = 0; i < 4; ++i) acc2[i] += vu.h[i] * wpk;

                k4 = k4n; v4 = v4n; valid = validn;
            }
        }

        // per-head denominator: sum over the 4 edge groups (lane bits 4,5)
        l += __shfl_xor(l, 16); l += __shfl_xor(l, 32);

        // reduce-scatter acc2[4] (8 dims) across the 4 groups, half2 adds
        const bool b1 = (g & 2) != 0;   // lane bit 5
        h2 r4[2];
        #pragma unroll
        for (int i = 0; i < 2; ++i) {
            h2 mine = b1 ? acc2[2 + i] : acc2[i];
            h2 send = b1 ? acc2[i] : acc2[2 + i];
            r4[i] = mine + shfl_h2(send, 32);
        }
        const bool b0 = (g & 1) != 0;   // lane bit 4
        h2 mine = b0 ? r4[1] : r4[0];
        h2 send = b0 ? r4[0] : r4[1];
        h2 r2 = mine + shfl_h2(send, 16);
        // lane (g,p) owns dims 8p + 2g, 8p + 2g + 1
        float inv = 1.0f / (l + 1e-16f);
        float o0 = gelu_exact((float)r2[0] * inv);
        float o1 = gelu_exact((float)r2[1] * inv);
        unsigned pk = h2_as_u(pkrtz(o0, o1));
        *reinterpret_cast<unsigned*>(oa + (size_t)n * 128 + p * 8 + 2 * g) = pk;
    }
}

// ---------------------------------------------------------------------------
// Final GEMM, LDS-free (both sides), f16 MFMA:
// out = sg*(oa_gelu @ Wo + bo) + (1-sg)*x.  dbuf weight frags, (256,3).
// ---------------------------------------------------------------------------
__global__ __launch_bounds__(256, 3) void final_mfma(
    const unsigned short* __restrict__ oa,   // [NN][128] f16, gelu'd
    const float* __restrict__ x_u, const unsigned short* __restrict__ F_u,
    const float* __restrict__ bo_u, const float* __restrict__ skip_u,
    const float* __restrict__ x_i, const unsigned short* __restrict__ F_i,
    const float* __restrict__ bo_i, const float* __restrict__ skip_i,
    float* __restrict__ out)
{
    const int t = threadIdx.x;
    const int side = blockIdx.x >= KQV_NB;
    const int m0 = (blockIdx.x - side * KQV_NB) * 128;
    const float* x = side ? x_i : x_u;
    const unsigned short* F = side ? F_i : F_u;
    const float* bo = side ? bo_i : bo_u;
    const float* skip = side ? skip_i : skip_u;
    const int row_off = side ? N_USERS : 0;
    const int M = N_USERS;

    const int wave = t >> 6, lane = t & 63;
    const int lr = lane & 15, lg = lane >> 4;
    const int rbase = m0 + wave * 32;

    h8 am[2][4];
    const h8 bz = {0, 0, 0, 0, 0, 0, 0, 0};
    #pragma unroll
    for (int mt = 0; mt < 2; ++mt)
        #pragma unroll
        for (int ks = 0; ks < 4; ++ks) {
            int row = rbase + mt * 16 + lr;
            am[mt][ks] = (row < M)
                ? *reinterpret_cast<const h8*>(
                      oa + (size_t)(row_off + row) * 128 + ks * 32 + lg * 8)
                : bz;
        }

    f32x4 acc[2][8];
    const f32x4 zero = {0.f, 0.f, 0.f, 0.f};
    #pragma unroll
    for (int mt = 0; mt < 2; ++mt)
        #pragma unroll
        for (int nt = 0; nt < 8; ++nt) acc[mt][nt] = zero;

    h8 bc[4], bn[4];
    #pragma unroll
    for (int ks = 0; ks < 4; ++ks)
        bc[ks] = *reinterpret_cast<const h8*>(
            F + ((size_t)(0 * 4 + ks) * 64 + lane) * 8);

    #pragma unroll
    for (int nt = 0; nt < 8; ++nt) {
        if (nt < 7) {
            #pragma unroll
            for (int ks = 0; ks < 4; ++ks)
                bn[ks] = *reinterpret_cast<const h8*>(
                    F + ((size_t)((nt + 1) * 4 + ks) * 64 + lane) * 8);
        }
        #pragma unroll
        for (int mt = 0; mt < 2; ++mt)
            #pragma unroll
            for (int ks = 0; ks < 4; ++ks)
                acc[mt][nt] = __builtin_amdgcn_mfma_f32_16x16x32_f16(
                    bc[ks], am[mt][ks], acc[mt][nt], 0, 0, 0);
        #pragma unroll
        for (int ks = 0; ks < 4; ++ks) bc[ks] = bn[ks];
    }

    const float sg = 1.0f / (1.0f + expf(-skip[0]));
    #pragma unroll
    for (int nt = 0; nt < 8; ++nt) {
        float4 bv = *reinterpret_cast<const float4*>(bo + nt * 16 + lg * 4);
        #pragma unroll
        for (int mt = 0; mt < 2; ++mt) {
            int row = rbase + mt * 16 + lr;
            if (row < M) {
                float4 xv = *reinterpret_cast<const float4*>(
                    x + (size_t)row * 128 + nt * 16 + lg * 4);
                float4 res;
                res.x = sg * (acc[mt][nt][0] + bv.x) + (1.f - sg) * xv.x;
                res.y = sg * (acc[mt][nt][1] + bv.y) + (1.f - sg) * xv.y;
                res.z = sg * (acc[mt][nt][2] + bv.z) + (1.f - sg) * xv.z;
                res.w = sg * (acc[mt][nt][3] + bv.w) + (1.f - sg) * xv.w;
                *reinterpret_cast<float4*>(
                    out + (size_t)(row_off + row) * 128 + nt * 16 + lg * 4) = res;
            }
        }
    }
}

// ---------------------------------------------------------------------------
extern "C" void kernel_launch(void* const* d_in, const int* in_sizes, int n_in,
                              void* d_out, int out_size, void* d_ws, size_t ws_size,
                              hipStream_t stream)
{
    const float* x_user     = (const float*)d_in[0];
    const float* x_item     = (const float*)d_in[1];
    const float* W_kqv_user = (const float*)d_in[2];
    const float* b_kqv_user = (const float*)d_in[3];
    const float* W_kqv_item = (const float*)d_in[4];
    const float* b_kqv_item = (const float*)d_in[5];
    const float* Wk_rel     = (const float*)d_in[6];
    const float* Wv_rel     = (const float*)d_in[7];
    const float* W_out_user = (const float*)d_in[8];
    const float* b_out_user = (const float*)d_in[9];
    const float* W_out_item = (const float*)d_in[10];
    const float* b_out_item = (const float*)d_in[11];
    const float* skip_user  = (const float*)d_in[12];
    const float* skip_item  = (const float*)d_in[13];
    const float* p_ui       = (const float*)d_in[14];
    const float* p_iu       = (const float*)d_in[15];
    const int*   edge_ui    = (const int*)d_in[16];
    const int*   edge_iu    = (const int*)d_in[17];

    const size_t NODE_F = (size_t)NN * FDIM;     // 12.8M elems
    char* w = (char*)d_ws;
    size_t off = 0;
    auto alloc = [&](size_t bytes) {
        char* p = w + off;
        off += (bytes + 255) & ~(size_t)255;
        return p;
    };
    unsigned short* q_b   = (unsigned short*)alloc(NODE_F * 2);
    unsigned short* kk_b  = (unsigned short*)alloc(NODE_F * 2);
    unsigned short* vv_b  = (unsigned short*)alloc(NODE_F * 2);
    unsigned short* oa_b  = (unsigned short*)alloc(NODE_F * 2);
    int* esrc   = (int*)alloc((size_t)E_TOT * 4);
    int* cnt    = (int*)alloc((size_t)NN * 4);
    int* base   = (int*)alloc((size_t)NN * 4);
    int* cursor = (int*)alloc((size_t)NN * 4);
    int* bsum   = (int*)alloc((size_t)SCAN_NB * 4);
    int2* meta2 = (int2*)alloc((size_t)NN * 8);
    unsigned short* F_u    = (unsigned short*)alloc(384 * 128 * 2);
    unsigned short* F_i    = (unsigned short*)alloc(384 * 128 * 2);
    float*          bias_u = (float*)alloc(384 * 4);
    float*          bias_i = (float*)alloc(384 * 4);
    unsigned short* Fo_u   = (unsigned short*)alloc(128 * 128 * 2);
    unsigned short* Fo_i   = (unsigned short*)alloc(128 * 128 * 2);

    // prep: kqv weights + wo weights + cnt zeroing (one launch)
    const int ZB = (NN + 511) / 512;   // 196
    prep_all<<<1024 + ZB, 128, 0, stream>>>(
        W_kqv_user, b_kqv_user, W_kqv_item, b_kqv_item, Wk_rel, Wv_rel,
        F_u, bias_u, F_i, bias_i,
        W_out_user, Fo_u, W_out_item, Fo_i, cnt);

    // edge histogram (separate: fusing into kqv spilled regs, R15 lesson)
    hist_kernel<<<(E_TOT + 255) / 256, 256, 0, stream>>>(edge_ui, edge_iu, cnt);

    // fused KQV(+rel) GEMM, both sides
    kqv_mfma<<<2 * KQV_NB, 256, 0, stream>>>(x_user, F_u, bias_u,
                                             x_item, F_i, bias_i,
                                             kk_b, q_b, vv_b);

    // CSR: scan + fill
    scan1_kernel<<<SCAN_NB, 256, 0, stream>>>(cnt, base, bsum);
    scan3_kernel<<<(NN + 255) / 256, 256, 0, stream>>>(base, bsum, cnt, cursor, meta2);
    fill_kernel<<<(E_TOT + 255) / 256, 256, 0, stream>>>(edge_ui, edge_iu, cursor, esrc);

    attn_fused<<<2048, 256, 0, stream>>>(q_b, kk_b, vv_b, meta2, esrc,
                                         p_ui, p_iu, oa_b);

    // final GEMM, both sides (gelu already applied in attn)
    final_mfma<<<2 * KQV_NB, 256, 0, stream>>>(
        oa_b, x_user, Fo_u, b_out_user, skip_user,
        x_item, Fo_i, b_out_item, skip_item, (float*)d_out);
}

// Round 18
// 229.593 us; speedup vs baseline: 1.0672x; 1.0316x over previous
//
#include <hip/hip_runtime.h>
#include <hip/hip_bf16.h>
#include <math.h>

#define N_USERS 50000
#define N_ITEMS 50000
#define NN      100000
#define HN      50000
#define E_PER_  400000
#define E_TOT   800000
#define FDIM    128
#define NH      4
#define HD      32
#define SCAN_CHUNK 1024
#define SCAN_NB    ((NN + SCAN_CHUNK - 1) / SCAN_CHUNK)   // 98
#define KQV_NB  ((N_USERS + 127) / 128)                   // 391 per side

typedef _Float16 h2 __attribute__((ext_vector_type(2)));
typedef _Float16 h8 __attribute__((ext_vector_type(8)));   // mfma f16 operand frag
typedef __attribute__((ext_vector_type(4))) float f32x4;

__device__ __forceinline__ float gelu_exact(float x) {
    return 0.5f * x * (1.0f + erff(x * 0.70710678118654752f));
}
__device__ __forceinline__ unsigned short f2h_bits(float f) {
    _Float16 h = (_Float16)f;
    union { _Float16 h; unsigned short u; } c; c.h = h; return c.u;
}
__device__ __forceinline__ h2 pkrtz(float a, float b) {
    return __builtin_bit_cast(h2, __builtin_amdgcn_cvt_pkrtz(a, b));
}
__device__ __forceinline__ unsigned h2_as_u(h2 x) {
    union { h2 h; unsigned u; } c; c.h = x; return c.u;
}
__device__ __forceinline__ h2 u_as_h2(unsigned x) {
    union { h2 h; unsigned u; } c; c.u = x; return c.h;
}
__device__ __forceinline__ h2 shfl_h2(h2 x, int m) {
    return u_as_h2((unsigned)__shfl_xor((int)h2_as_u(x), m));
}
// fragment slot index for A-operand W (16B per lane): n = matrix row, k = contraction
__device__ __forceinline__ size_t wfrag_idx(int n, int k) {
    int ch = n >> 7, nt = (n >> 4) & 7, lr = n & 15;
    int ks = k >> 5, lg = (k >> 3) & 3, e = k & 7;
    return ((size_t)(((ch * 8 + nt) * 4 + ks) * 64 + lg * 16 + lr)) * 8 + e;
}

// ---------------------------------------------------------------------------
// prep_all: [0,768) kqv-weight prep (rel-fused, frag layout);
//           [768,1024) W_out prep; [1024,...) zero cnt.  128 thr/block.
// ---------------------------------------------------------------------------
__global__ void prep_all(
    const float* __restrict__ W_u, const float* __restrict__ b_u,
    const float* __restrict__ W_i, const float* __restrict__ b_i,
    const float* __restrict__ Wk_rel, const float* __restrict__ Wv_rel,
    unsigned short* __restrict__ F_u, float* __restrict__ bias_u,
    unsigned short* __restrict__ F_i, float* __restrict__ bias_i,
    const float* __restrict__ Wo_u, unsigned short* __restrict__ Fo_u,
    const float* __restrict__ Wo_i, unsigned short* __restrict__ Fo_i,
    int* __restrict__ cnt)
{
    const int bid = blockIdx.x;
    if (bid < 768) {
        const int et = bid >= 384;
        const int n = bid - et * 384;   // 0..383
        const int k = threadIdx.x;      // 0..127
        const float* W = et ? W_i : W_u;
        const float* b = et ? b_i : b_u;
        unsigned short* F = et ? F_i : F_u;
        float* bias_f = et ? bias_i : bias_u;
        float s;
        if (n < 128) {
            int h = n >> 5, e = n & 31;
            const float* wr = Wk_rel + (size_t)(h * 2 + et) * 1024 + e;
            const float* wc = W + (size_t)k * 384 + h * 32;
            s = 0.f;
            for (int d = 0; d < 32; ++d) s = fmaf(wc[d], wr[d * 32], s);
            if (k == 0) {
                float bs = 0.f;
                for (int d = 0; d < 32; ++d) bs = fmaf(b[h * 32 + d], wr[d * 32], bs);
                bias_f[n] = bs;
            }
        } else if (n < 256) {
            s = W[(size_t)k * 384 + n];
            if (k == 0) bias_f[n] = b[n];
        } else {
            int h = (n - 256) >> 5, e = (n - 256) & 31;
            const float* wr = Wv_rel + (size_t)(h * 2 + et) * 1024 + e;
            const float* wc = W + (size_t)k * 384 + 256 + h * 32;
            s = 0.f;
            for (int d = 0; d < 32; ++d) s = fmaf(wc[d], wr[d * 32], s);
            if (k == 0) {
                float bs = 0.f;
                for (int d = 0; d < 32; ++d) bs = fmaf(b[256 + h * 32 + d], wr[d * 32], bs);
                bias_f[n] = bs;
            }
        }
        F[wfrag_idx(n, k)] = f2h_bits(s);
    } else if (bid < 1024) {
        int i = (bid - 768) * 128 + threadIdx.x;   // 0..32767
        int side = i >= 16384;
        int j = i - side * 16384;
        int n = j >> 7, k = j & 127;
        const float* W = side ? Wo_i : Wo_u;
        unsigned short* F = side ? Fo_i : Fo_u;
        F[wfrag_idx(n, k)] = f2h_bits(W[(size_t)k * 128 + n]);
    } else {
        int i = (bid - 1024) * 512 + threadIdx.x * 4;
        #pragma unroll
        for (int j = 0; j < 4; ++j)
            if (i + j < NN) cnt[i + j] = 0;
    }
}

// ---------------------------------------------------------------------------
// CSR helpers
// ---------------------------------------------------------------------------
__device__ __forceinline__ void edge_src_dst(
    int e, const int* __restrict__ edge_ui, const int* __restrict__ edge_iu,
    int& src, int& dst)
{
    if (e < E_PER_) {
        src = edge_ui[e];
        dst = edge_ui[E_PER_ + e] + N_USERS;
    } else {
        int e2 = e - E_PER_;
        src = N_USERS + edge_iu[e2];
        dst = edge_iu[E_PER_ + e2];
    }
}

__global__ __launch_bounds__(256) void hist_kernel(
    const int* __restrict__ edge_ui, const int* __restrict__ edge_iu,
    int* __restrict__ cnt)
{
    int e = blockIdx.x * blockDim.x + threadIdx.x;
    if (e >= E_TOT) return;
    int src, dst;
    edge_src_dst(e, edge_ui, edge_iu, src, dst);
    atomicAdd(cnt + dst, 1);
}

// ---------------------------------------------------------------------------
// KQV GEMM, LDS-free, f16 MFMA. BM=128, 3 chunks.
// k and v write into ONE interleaved kv array (node row = 512B: k|v) so the
// attn gather touches a single contiguous 512B block per edge.
// ---------------------------------------------------------------------------
__global__ __launch_bounds__(256, 3) void kqv_mfma(
    const float* __restrict__ X_u, const unsigned short* __restrict__ F_u,
    const float* __restrict__ bias_u,
    const float* __restrict__ X_i, const unsigned short* __restrict__ F_i,
    const float* __restrict__ bias_i,
    unsigned short* __restrict__ kv_b,   // [NN][256] f16: k(0:128) v(128:256)
    unsigned short* __restrict__ q_b)    // [NN][128]
{
    const int t = threadIdx.x;
    const int side = blockIdx.x >= KQV_NB;
    const int m0 = (blockIdx.x - side * KQV_NB) * 128;
    const float* X = side ? X_i : X_u;
    const unsigned short* F = side ? F_i : F_u;
    const float* bias = side ? bias_i : bias_u;
    const int side_off = side ? N_USERS : 0;
    const int M = N_USERS;

    const int wave = t >> 6, lane = t & 63;
    const int lr = lane & 15, lg = lane >> 4;
    const int rbase = m0 + wave * 32;

    h8 am[2][4];
    #pragma unroll
    for (int mt = 0; mt < 2; ++mt)
        #pragma unroll
        for (int ks = 0; ks < 4; ++ks) {
            int row = rbase + mt * 16 + lr;
            float4 a = make_float4(0.f, 0.f, 0.f, 0.f);
            float4 b4 = make_float4(0.f, 0.f, 0.f, 0.f);
            if (row < M) {
                const float* px = X + (size_t)row * 128 + ks * 32 + lg * 8;
                a  = *reinterpret_cast<const float4*>(px);
                b4 = *reinterpret_cast<const float4*>(px + 4);
            }
            union { h2 q[4]; h8 f; } u;
            u.q[0] = pkrtz(a.x, a.y);
            u.q[1] = pkrtz(a.z, a.w);
            u.q[2] = pkrtz(b4.x, b4.y);
            u.q[3] = pkrtz(b4.z, b4.w);
            am[mt][ks] = u.f;
        }

    #pragma unroll
    for (int ch = 0; ch < 3; ++ch) {
        f32x4 acc[2][8];
        const f32x4 zero = {0.f, 0.f, 0.f, 0.f};
        #pragma unroll
        for (int mt = 0; mt < 2; ++mt)
            #pragma unroll
            for (int nt = 0; nt < 8; ++nt) acc[mt][nt] = zero;

        h8 bc[4], bn[4];
        #pragma unroll
        for (int ks = 0; ks < 4; ++ks)
            bc[ks] = *reinterpret_cast<const h8*>(
                F + ((size_t)((ch * 8 + 0) * 4 + ks) * 64 + lane) * 8);

        #pragma unroll
        for (int nt = 0; nt < 8; ++nt) {
            if (nt < 7) {
                #pragma unroll
                for (int ks = 0; ks < 4; ++ks)
                    bn[ks] = *reinterpret_cast<const h8*>(
                        F + ((size_t)((ch * 8 + nt + 1) * 4 + ks) * 64 + lane) * 8);
            }
            #pragma unroll
            for (int mt = 0; mt < 2; ++mt)
                #pragma unroll
                for (int ks = 0; ks < 4; ++ks)
                    acc[mt][nt] = __builtin_amdgcn_mfma_f32_16x16x32_f16(
                        bc[ks], am[mt][ks], acc[mt][nt], 0, 0, 0);
            #pragma unroll
            for (int ks = 0; ks < 4; ++ks) bc[ks] = bn[ks];
        }

        // ch 0 -> kv[...][0:128] (k); ch 1 -> q; ch 2 -> kv[...][128:256] (v)
        unsigned short* arr = (ch == 1) ? q_b : kv_b;
        const int rstride = (ch == 1) ? 128 : 256;
        const int coff = (ch == 2) ? 128 : 0;
        #pragma unroll
        for (int nt = 0; nt < 8; ++nt) {
            float4 bv = *reinterpret_cast<const float4*>(bias + ch * 128 + nt * 16 + lg * 4);
            #pragma unroll
            for (int mt = 0; mt < 2; ++mt) {
                int row = rbase + mt * 16 + lr;
                if (row < M) {
                    h2 lo = pkrtz(acc[mt][nt][0] + bv.x, acc[mt][nt][1] + bv.y);
                    h2 hi = pkrtz(acc[mt][nt][2] + bv.z, acc[mt][nt][3] + bv.w);
                    uint2 st = make_uint2(h2_as_u(lo), h2_as_u(hi));
                    *reinterpret_cast<uint2*>(
                        arr + (size_t)(side_off + row) * rstride + coff + nt * 16 + lg * 4) = st;
                }
            }
        }
    }
}

// ---------------------------------------------------------------------------
// scan1: per-1024-chunk exclusive scan of cnt -> base, chunk totals -> bsum
// ---------------------------------------------------------------------------
__global__ __launch_bounds__(256) void scan1_kernel(
    const int* __restrict__ cnt, int* __restrict__ base, int* __restrict__ bsum)
{
    __shared__ int ssum[256];
    const int t = threadIdx.x;
    const int i0 = blockIdx.x * SCAN_CHUNK + t * 4;
    int v[4];
    #pragma unroll
    for (int j = 0; j < 4; ++j) v[j] = (i0 + j < NN) ? cnt[i0 + j] : 0;
    int tsum = v[0] + v[1] + v[2] + v[3];
    ssum[t] = tsum;
    __syncthreads();
    int run = tsum;
    for (int off = 1; off < 256; off <<= 1) {
        int o = (t >= off) ? ssum[t - off] : 0;
        __syncthreads();
        run += o;
        ssum[t] = run;
        __syncthreads();
    }
    int excl = run - tsum;
    int p = excl;
    #pragma unroll
    for (int j = 0; j < 4; ++j) {
        if (i0 + j < NN) base[i0 + j] = p;
        p += v[j];
    }
    if (t == 255) bsum[blockIdx.x] = run;
}

// scan3: adds chunk-prefix of bsum; writes cursor and packed (base,cnt) meta.
__global__ __launch_bounds__(256) void scan3_kernel(
    const int* __restrict__ base, const int* __restrict__ bsum,
    const int* __restrict__ cnt,
    int* __restrict__ cursor, int2* __restrict__ meta2)
{
    const int lane = threadIdx.x & 63;
    const int chunk = blockIdx.x >> 2;          // 256 threads, 1024-chunks
    int v0 = (lane < chunk) ? bsum[lane] : 0;
    int v1 = (64 + lane < chunk && 64 + lane < SCAN_NB) ? bsum[64 + lane] : 0;
    int s = v0 + v1;
    #pragma unroll
    for (int off = 1; off < 64; off <<= 1) s += __shfl_xor(s, off);
    int i = blockIdx.x * 256 + threadIdx.x;
    if (i < NN) {
        int b = base[i] + s;
        cursor[i] = b;
        meta2[i] = make_int2(b, cnt[i]);
    }
}

__global__ __launch_bounds__(256) void fill_kernel(
    const int* __restrict__ edge_ui, const int* __restrict__ edge_iu,
    int* __restrict__ cursor, int* __restrict__ esrc)
{
    int e = blockIdx.x * blockDim.x + threadIdx.x;
    if (e >= E_TOT) return;
    int src, dst;
    edge_src_dst(e, edge_ui, edge_iu, src, dst);
    int pos = atomicAdd(cursor + dst, 1);
    esrc[pos] = src;
}

// ---------------------------------------------------------------------------
// Fused attention v9 (f16, 1-node/wave, interleaved kv): FOUR edges/iter
// (g=lane>>4, p=lane&15, head h=p>>2), intra-node prefetch, direct exp,
// fdot2 QK, half2 PV, reduce-scatter + all-lane gelu epilogue.
// k and v now come from ONE 512B block per edge (single random region).
// ---------------------------------------------------------------------------
__global__ __launch_bounds__(256) void attn_fused(
    const unsigned short* __restrict__ q_b, const unsigned short* __restrict__ kv_b,
    const int2* __restrict__ meta2, const int* __restrict__ esrc,
    const float* __restrict__ p_ui, const float* __restrict__ p_iu,
    unsigned short* __restrict__ oa)
{
    const int wid  = (blockIdx.x * blockDim.x + threadIdx.x) >> 6;
    const int lane = threadIdx.x & 63;
    const int nw   = (gridDim.x * blockDim.x) >> 6;
    const int g    = lane >> 4;      // edge slot 0..3
    const int p    = lane & 15;      // dims 8p..8p+7
    const int h    = p >> 2;         // head
    const float rsd = 0.17677669529663687f;   // 1/sqrt(32)
    const float pu = p_ui[h], pi = p_iu[h];

    for (int n = wid; n < NN; n += nw) {
        const float pr = (n >= N_USERS) ? pu : pi;
        union { uint4 u; h2 h[4]; } qu;
        qu.u = *reinterpret_cast<const uint4*>(q_b + (size_t)n * 128 + p * 8);
        float l = 0.f;
        h2 acc2[4];
        #pragma unroll
        for (int i = 0; i < 4; ++i) acc2[i] = (h2)(_Float16)0;
        const int2 mt = meta2[n];
        const int s0 = mt.x, c = mt.y;

        if (c > 0) {
            bool valid = g < c;
            int src = esrc[s0 + (valid ? g : 0)];
            const unsigned short* kvrow = kv_b + (size_t)src * 256 + p * 8;
            uint4 k4 = *reinterpret_cast<const uint4*>(kvrow);
            uint4 v4 = *reinterpret_cast<const uint4*>(kvrow + 128);

            for (int j = 0; j < c; j += 4) {
                uint4 k4n, v4n;
                bool validn = false;
                if (j + 4 < c) {
                    int jn = j + 4 + g;
                    validn = jn < c;
                    int srcn = esrc[s0 + (validn ? jn : 0)];
                    const unsigned short* kvn = kv_b + (size_t)srcn * 256 + p * 8;
                    k4n = *reinterpret_cast<const uint4*>(kvn);
                    v4n = *reinterpret_cast<const uint4*>(kvn + 128);
                }

                union { uint4 u; h2 h[4]; } ku, vu;
                ku.u = k4; vu.u = v4;
                float s = 0.f;
                s = __builtin_amdgcn_fdot2(qu.h[0], ku.h[0], s, false);
                s = __builtin_amdgcn_fdot2(qu.h[1], ku.h[1], s, false);
                s = __builtin_amdgcn_fdot2(qu.h[2], ku.h[2], s, false);
                s = __builtin_amdgcn_fdot2(qu.h[3], ku.h[3], s, false);
                s += __shfl_xor(s, 1);
                s += __shfl_xor(s, 2);       // head = 4 lanes x 8 dims
                float w = valid ? __expf(s * pr * rsd) : 0.f;
                l += w;
                h2 wpk = pkrtz(w, w);
                #pragma unroll
                for (int i = 0; i < 4; ++i) acc2[i] += vu.h[i] * wpk;

                k4 = k4n; v4 = v4n; valid = validn;
            }
        }

        // per-head denominator: sum over the 4 edge groups (lane bits 4,5)
        l += __shfl_xor(l, 16); l += __shfl_xor(l, 32);

        // reduce-scatter acc2[4] (8 dims) across the 4 groups, half2 adds
        const bool b1 = (g & 2) != 0;   // lane bit 5
        h2 r4[2];
        #pragma unroll
        for (int i = 0; i < 2; ++i) {
            h2 mine = b1 ? acc2[2 + i] : acc2[i];
            h2 send = b1 ? acc2[i] : acc2[2 + i];
            r4[i] = mine + shfl_h2(send, 32);
        }
        const bool b0 = (g & 1) != 0;   // lane bit 4
        h2 mine = b0 ? r4[1] : r4[0];
        h2 send = b0 ? r4[0] : r4[1];
        h2 r2 = mine + shfl_h2(send, 16);
        // lane (g,p) owns dims 8p + 2g, 8p + 2g + 1
        float inv = 1.0f / (l + 1e-16f);
        float o0 = gelu_exact((float)r2[0] * inv);
        float o1 = gelu_exact((float)r2[1] * inv);
        unsigned pk = h2_as_u(pkrtz(o0, o1));
        *reinterpret_cast<unsigned*>(oa + (size_t)n * 128 + p * 8 + 2 * g) = pk;
    }
}

// ---------------------------------------------------------------------------
// Final GEMM, LDS-free (both sides), f16 MFMA:
// out = sg*(oa_gelu @ Wo + bo) + (1-sg)*x.  dbuf weight frags, (256,3).
// ---------------------------------------------------------------------------
__global__ __launch_bounds__(256, 3) void final_mfma(
    const unsigned short* __restrict__ oa,   // [NN][128] f16, gelu'd
    const float* __restrict__ x_u, const unsigned short* __restrict__ F_u,
    const float* __restrict__ bo_u, const float* __restrict__ skip_u,
    const float* __restrict__ x_i, const unsigned short* __restrict__ F_i,
    const float* __restrict__ bo_i, const float* __restrict__ skip_i,
    float* __restrict__ out)
{
    const int t = threadIdx.x;
    const int side = blockIdx.x >= KQV_NB;
    const int m0 = (blockIdx.x - side * KQV_NB) * 128;
    const float* x = side ? x_i : x_u;
    const unsigned short* F = side ? F_i : F_u;
    const float* bo = side ? bo_i : bo_u;
    const float* skip = side ? skip_i : skip_u;
    const int row_off = side ? N_USERS : 0;
    const int M = N_USERS;

    const int wave = t >> 6, lane = t & 63;
    const int lr = lane & 15, lg = lane >> 4;
    const int rbase = m0 + wave * 32;

    h8 am[2][4];
    const h8 bz = {0, 0, 0, 0, 0, 0, 0, 0};
    #pragma unroll
    for (int mt = 0; mt < 2; ++mt)
        #pragma unroll
        for (int ks = 0; ks < 4; ++ks) {
            int row = rbase + mt * 16 + lr;
            am[mt][ks] = (row < M)
                ? *reinterpret_cast<const h8*>(
                      oa + (size_t)(row_off + row) * 128 + ks * 32 + lg * 8)
                : bz;
        }

    f32x4 acc[2][8];
    const f32x4 zero = {0.f, 0.f, 0.f, 0.f};
    #pragma unroll
    for (int mt = 0; mt < 2; ++mt)
        #pragma unroll
        for (int nt = 0; nt < 8; ++nt) acc[mt][nt] = zero;

    h8 bc[4], bn[4];
    #pragma unroll
    for (int ks = 0; ks < 4; ++ks)
        bc[ks] = *reinterpret_cast<const h8*>(
            F + ((size_t)(0 * 4 + ks) * 64 + lane) * 8);

    #pragma unroll
    for (int nt = 0; nt < 8; ++nt) {
        if (nt < 7) {
            #pragma unroll
            for (int ks = 0; ks < 4; ++ks)
                bn[ks] = *reinterpret_cast<const h8*>(
                    F + ((size_t)((nt + 1) * 4 + ks) * 64 + lane) * 8);
        }
        #pragma unroll
        for (int mt = 0; mt < 2; ++mt)
            #pragma unroll
            for (int ks = 0; ks < 4; ++ks)
                acc[mt][nt] = __builtin_amdgcn_mfma_f32_16x16x32_f16(
                    bc[ks], am[mt][ks], acc[mt][nt], 0, 0, 0);
        #pragma unroll
        for (int ks = 0; ks < 4; ++ks) bc[ks] = bn[ks];
    }

    const float sg = 1.0f / (1.0f + expf(-skip[0]));
    #pragma unroll
    for (int nt = 0; nt < 8; ++nt) {
        float4 bv = *reinterpret_cast<const float4*>(bo + nt * 16 + lg * 4);
        #pragma unroll
        for (int mt = 0; mt < 2; ++mt) {
            int row = rbase + mt * 16 + lr;
            if (row < M) {
                float4 xv = *reinterpret_cast<const float4*>(
                    x + (size_t)row * 128 + nt * 16 + lg * 4);
                float4 res;
                res.x = sg * (acc[mt][nt][0] + bv.x) + (1.f - sg) * xv.x;
                res.y = sg * (acc[mt][nt][1] + bv.y) + (1.f - sg) * xv.y;
                res.z = sg * (acc[mt][nt][2] + bv.z) + (1.f - sg) * xv.z;
                res.w = sg * (acc[mt][nt][3] + bv.w) + (1.f - sg) * xv.w;
                *reinterpret_cast<float4*>(
                    out + (size_t)(row_off + row) * 128 + nt * 16 + lg * 4) = res;
            }
        }
    }
}

// ---------------------------------------------------------------------------
extern "C" void kernel_launch(void* const* d_in, const int* in_sizes, int n_in,
                              void* d_out, int out_size, void* d_ws, size_t ws_size,
                              hipStream_t stream)
{
    const float* x_user     = (const float*)d_in[0];
    const float* x_item     = (const float*)d_in[1];
    const float* W_kqv_user = (const float*)d_in[2];
    const float* b_kqv_user = (const float*)d_in[3];
    const float* W_kqv_item = (const float*)d_in[4];
    const float* b_kqv_item = (const float*)d_in[5];
    const float* Wk_rel     = (const float*)d_in[6];
    const float* Wv_rel     = (const float*)d_in[7];
    const float* W_out_user = (const float*)d_in[8];
    const float* b_out_user = (const float*)d_in[9];
    const float* W_out_item = (const float*)d_in[10];
    const float* b_out_item = (const float*)d_in[11];
    const float* skip_user  = (const float*)d_in[12];
    const float* skip_item  = (const float*)d_in[13];
    const float* p_ui       = (const float*)d_in[14];
    const float* p_iu       = (const float*)d_in[15];
    const int*   edge_ui    = (const int*)d_in[16];
    const int*   edge_iu    = (const int*)d_in[17];

    const size_t NODE_F = (size_t)NN * FDIM;     // 12.8M elems
    char* w = (char*)d_ws;
    size_t off = 0;
    auto alloc = [&](size_t bytes) {
        char* p = w + off;
        off += (bytes + 255) & ~(size_t)255;
        return p;
    };
    unsigned short* kv_b  = (unsigned short*)alloc(NODE_F * 4);   // [NN][256]
    unsigned short* q_b   = (unsigned short*)alloc(NODE_F * 2);
    unsigned short* oa_b  = (unsigned short*)alloc(NODE_F * 2);
    int* esrc   = (int*)alloc((size_t)E_TOT * 4);
    int* cnt    = (int*)alloc((size_t)NN * 4);
    int* base   = (int*)alloc((size_t)NN * 4);
    int* cursor = (int*)alloc((size_t)NN * 4);
    int* bsum   = (int*)alloc((size_t)SCAN_NB * 4);
    int2* meta2 = (int2*)alloc((size_t)NN * 8);
    unsigned short* F_u    = (unsigned short*)alloc(384 * 128 * 2);
    unsigned short* F_i    = (unsigned short*)alloc(384 * 128 * 2);
    float*          bias_u = (float*)alloc(384 * 4);
    float*          bias_i = (float*)alloc(384 * 4);
    unsigned short* Fo_u   = (unsigned short*)alloc(128 * 128 * 2);
    unsigned short* Fo_i   = (unsigned short*)alloc(128 * 128 * 2);

    // prep: kqv weights + wo weights + cnt zeroing (one launch)
    const int ZB = (NN + 511) / 512;   // 196
    prep_all<<<1024 + ZB, 128, 0, stream>>>(
        W_kqv_user, b_kqv_user, W_kqv_item, b_kqv_item, Wk_rel, Wv_rel,
        F_u, bias_u, F_i, bias_i,
        W_out_user, Fo_u, W_out_item, Fo_i, cnt);

    // edge histogram (separate: fusing into kqv spilled regs, R15 lesson)
    hist_kernel<<<(E_TOT + 255) / 256, 256, 0, stream>>>(edge_ui, edge_iu, cnt);

    // fused KQV(+rel) GEMM, both sides, interleaved kv output
    kqv_mfma<<<2 * KQV_NB, 256, 0, stream>>>(x_user, F_u, bias_u,
                                             x_item, F_i, bias_i,
                                             kv_b, q_b);

    // CSR: scan + fill
    scan1_kernel<<<SCAN_NB, 256, 0, stream>>>(cnt, base, bsum);
    scan3_kernel<<<(NN + 255) / 256, 256, 0, stream>>>(base, bsum, cnt, cursor, meta2);
    fill_kernel<<<(E_TOT + 255) / 256, 256, 0, stream>>>(edge_ui, edge_iu, cursor, esrc);

    attn_fused<<<2048, 256, 0, stream>>>(q_b, kv_b, meta2, esrc,
                                         p_ui, p_iu, oa_b);

    // final GEMM, both sides (gelu already applied in attn)
    final_mfma<<<2 * KQV_NB, 256, 0, stream>>>(
        oa_b, x_user, Fo_u, b_out_user, skip_user,
        x_item, Fo_i, b_out_item, skip_item, (float*)d_out);
}